// Round 3
// baseline (356.053 us; speedup 1.0000x reference)
//
#include <hip/hip_runtime.h>
#include <math.h>

#define B_ROWS 2048
#define C_COLS 32000
#define L_LABELS 8
#define GAMMA_W 0.2f
#define BIG_V 100000000.0f

#define TPB1 320                    // 5 waves
#define F4T 5                       // float4 per thread in k1
#define CPR 5                       // chunks (blocks) per row: 5*320*5 = 8000 f4 = 32000 floats
#define NBLK1 (B_ROWS * CPR)        // 10240 blocks

// k1: pure streaming exp-sum. Each block owns a contiguous 1600-float4 chunk
// (quarter... fifth of a row). 5 independent loads in flight per thread,
// low VGPR -> 8 waves/SIMD. Writes one partial per block.
__global__ __launch_bounds__(TPB1) void
rll_k1_sum(const float* __restrict__ x, float* __restrict__ part) {
    const int blk = blockIdx.x;
    const int row = blk / CPR;
    const int chunk = blk - row * CPR;
    const int tid = threadIdx.x;
    const float4* __restrict__ x4 =
        reinterpret_cast<const float4*>(x + (size_t)row * C_COLS) + chunk * (TPB1 * F4T);

    float4 buf[F4T];
    #pragma unroll
    for (int k = 0; k < F4T; ++k) buf[k] = x4[tid + k * TPB1];

    float s0 = 0.f, s1 = 0.f, s2 = 0.f, s3 = 0.f;
    #pragma unroll
    for (int k = 0; k < F4T; ++k) {
        s0 += __expf(buf[k].x);
        s1 += __expf(buf[k].y);
        s2 += __expf(buf[k].z);
        s3 += __expf(buf[k].w);
    }
    float s = (s0 + s1) + (s2 + s3);

    #pragma unroll
    for (int off = 32; off > 0; off >>= 1) s += __shfl_xor(s, off, 64);

    __shared__ float ss[TPB1 / 64];
    if ((tid & 63) == 0) ss[tid >> 6] = s;
    __syncthreads();

    if (tid == 0) {
        float t = ss[0];
        #pragma unroll
        for (int w = 1; w < TPB1 / 64; ++w) t += ss[w];
        part[blk] = t;
    }
}

// k2: per-row label math. One thread per row: sum the 5 chunk partials,
// gather <=8 label logits, compute loss1 contribution and masked-LSE loss2.
__global__ __launch_bounds__(256) void
rll_k2_row(const float* __restrict__ x, const int* __restrict__ y,
           const float* __restrict__ part, float* __restrict__ prow) {
    const int row = blockIdx.x * 256 + threadIdx.x;  // grid = 8 blocks

    float s = 0.f;
    #pragma unroll
    for (int c = 0; c < CPR; ++c) s += part[row * CPR + c];
    const float logZ = logf(s);

    const float* __restrict__ xr = x + (size_t)row * C_COLS;
    const int* __restrict__ yr = y + row * L_LABELS;
    int idx[L_LABELS];
    #pragma unroll
    for (int i = 0; i < L_LABELS; ++i) idx[i] = yr[i];

    float xv[L_LABELS];
    xv[0] = xr[idx[0]];
    float minrel = BIG_V;
    bool any_rel = false;
    #pragma unroll
    for (int i = 1; i < L_LABELS; ++i) {
        if (idx[i] >= 0) {
            float v = xr[idx[i]];
            xv[i] = v;
            minrel = fminf(minrel, v);
            any_rel = true;
        }
    }

    const float loss1_contrib = logZ - xv[0];

    float contrib2 = 0.f, cnt = 0.f;
    if (any_rel) {
        // subtract unique marked columns' exp(x) from the unshifted row sum
        float sub = 0.f;
        #pragma unroll
        for (int i = 0; i < L_LABELS; ++i) {
            const bool vi = (i == 0) || (idx[i] >= 0);
            if (!vi) continue;
            bool dup = false;
            #pragma unroll
            for (int j = 0; j < i; ++j) {
                const bool vj = (j == 0) || (idx[j] >= 0);
                if (vj && idx[j] == idx[i]) dup = true;
            }
            if (!dup) sub += expf(xv[i]);
        }
        float s_new = fmaxf(s - sub, 1e-30f);
        const float lse_new = logf(s_new);

        // loss_row = logaddexp(minrel, lse_new) - minrel
        const float a = minrel, b = lse_new;
        const float mx = fmaxf(a, b);
        contrib2 = (mx + log1pf(expf(-fabsf(a - b)))) - a;
        cnt = 1.f;
    }

    prow[row] = loss1_contrib;
    prow[B_ROWS + row] = contrib2;
    prow[2 * B_ROWS + row] = cnt;
}

// k3: reduce the 3 x 2048 per-row arrays to the scalar loss.
__global__ __launch_bounds__(1024) void
rll_k3_reduce(const float* __restrict__ p, float* __restrict__ out) {
    const int tid = threadIdx.x;
    float a = p[tid] + p[tid + 1024];
    float b = p[2048 + tid] + p[3072 + tid];
    float c = p[4096 + tid] + p[5120 + tid];

    #pragma unroll
    for (int off = 32; off > 0; off >>= 1) {
        a += __shfl_xor(a, off, 64);
        b += __shfl_xor(b, off, 64);
        c += __shfl_xor(c, off, 64);
    }

    __shared__ float sa[16], sb[16], sc[16];
    const int wave = tid >> 6;
    if ((tid & 63) == 0) { sa[wave] = a; sb[wave] = b; sc[wave] = c; }
    __syncthreads();

    if (tid == 0) {
        float ta = 0.f, tb = 0.f, tc = 0.f;
        #pragma unroll
        for (int w = 0; w < 16; ++w) { ta += sa[w]; tb += sb[w]; tc += sc[w]; }
        const float loss1 = ta / (float)B_ROWS;
        const float loss2 = tb / fmaxf(tc, 1.0f);
        out[0] = loss1 + GAMMA_W * loss2;
    }
}

extern "C" void kernel_launch(void* const* d_in, const int* in_sizes, int n_in,
                              void* d_out, int out_size, void* d_ws, size_t ws_size,
                              hipStream_t stream) {
    const float* x = (const float*)d_in[0];
    const int* yy = (const int*)d_in[1];
    float* out = (float*)d_out;
    float* part = (float*)d_ws;             // [0, 10240) block partials
    float* prow = part + NBLK1;             // [10240, 10240+3*2048) per-row values

    rll_k1_sum<<<NBLK1, TPB1, 0, stream>>>(x, part);
    rll_k2_row<<<B_ROWS / 256, 256, 0, stream>>>(x, yy, part, prow);
    rll_k3_reduce<<<1, 1024, 0, stream>>>(prow, out);
}